// Round 6
// baseline (156.678 us; speedup 1.0000x reference)
//
#include <hip/hip_runtime.h>
#include <stdint.h>

// VectorQuantizer on MI355X — round 5: 3-blocks/CU argmin (24 KB LDS chunks),
// merged prep dispatch. Chunk-planar conflict-free staging throughout.
// latent [32,256,1024] fp32, codebook [1024,256] fp32.
// d_out float regions: Xt bf16 [0,4194304) | Ebf bf16 [4194304,4325376)
// | e2 [4325376,4326400) — consumed by k_argmin, overwritten by k_out's q_st.
// ws = packed u64[32768]: atomicMin of {monotone_score_key:32 | k:32}.

#define D_   256
#define HW_  1024
#define N_   32768
#define K_   1024

typedef __attribute__((ext_vector_type(8))) short  s8v;   // 8 bf16 (4 VGPR)
typedef __attribute__((ext_vector_type(4))) float  f4v;   // MFMA acc

__device__ __forceinline__ ushort bf16rne(float x) {
  unsigned u = __float_as_uint(x);
  return (ushort)((u + 0x7FFFu + ((u >> 16) & 1u)) >> 16);
}

// monotone map: unsigned order of key == float order (handles negatives)
__device__ __forceinline__ unsigned fkey(float f) {
  unsigned u = __float_as_uint(f);
  return u ^ (unsigned)(((int)u >> 31) | 0x80000000);
}

// async global->LDS DMA, 16 B/lane; LDS dest = wave-uniform base + lane*16
__device__ __forceinline__ void gld_lds16(const void* g, void* l) {
  __builtin_amdgcn_global_load_lds(
      (const __attribute__((address_space(1))) unsigned int*)g,
      (__attribute__((address_space(3))) unsigned int*)l, 16, 0, 0);
}

// ---------- merged prep: blocks 0..255 xprep, 256..319 eprep ----------
// xprep: latent -> bf16 chunk-planar Xt [tile(256)][dq(32)][pos(128)][8],
//        + packed init. eprep: cb -> bf16 chunk-planar Ebf [dq(32)][code(1024)][8]
//        + numpy-pairwise e2 + loss zero.
__global__ __launch_bounds__(256) void k_prep(const float* __restrict__ latent,
                                              const float* __restrict__ cb,
                                              ushort* __restrict__ Xt,
                                              ushort* __restrict__ Ebf,
                                              float* __restrict__ e2,
                                              unsigned long long* __restrict__ packed,
                                              float* __restrict__ loss) {
  const int t = threadIdx.x;
  if (blockIdx.x < 256) {
    __shared__ float Xf[64 * 132];                 // 33 KB, pitch 132 (16B-aligned)
    const int tile = blockIdx.x;                   // 256 tiles x 128 pos
    int gid = tile * 256 + t;
    if (gid < N_) packed[gid] = ~0ull;             // init argmin keys
    const int b = tile >> 3, hw0 = (tile & 7) * 128;
    const float* Lb = latent + (size_t)b * (D_ * HW_) + hw0;
    for (int s = 0; s < 4; ++s) {                  // 4 slabs of 64 d
      __syncthreads();
#pragma unroll
      for (int it = 0; it < 8; ++it) {             // load [64 d][128 hw] fp32
        int idx = it * 256 + t;
        int d = idx >> 5, hq = idx & 31;
        float4 v = *(const float4*)(Lb + (size_t)(s * 64 + d) * HW_ + hq * 4);
        *(float4*)&Xf[d * 132 + hq * 4] = v;
      }
      __syncthreads();
#pragma unroll
      for (int it = 0; it < 4; ++it) {             // transpose-convert out
        int idx = it * 256 + t;
        int pos = idx & 127, dq = idx >> 7;        // dq 0..7 within slab
        ushort tmp[8] __attribute__((aligned(16)));
#pragma unroll
        for (int e = 0; e < 8; ++e) tmp[e] = bf16rne(Xf[(dq * 8 + e) * 132 + pos]);
        *(uint4*)(Xt + ((size_t)(tile * 32 + s * 8 + dq) * 128 + pos) * 8) =
            *(uint4*)tmp;
      }
    }
  } else {
    const int blk = blockIdx.x - 256;              // 64 blocks x 16 codes
    if (blk == 0 && t == 0) *loss = 0.f;
#pragma unroll
    for (int it = 0; it < 2; ++it) {
      int c = it * 256 + t;                        // 512 chunks/block
      int cl = c & 15, dq = c >> 4;                // code-local, d-chunk
      const float* src = cb + (size_t)(blk * 16 + cl) * 256 + dq * 8;
      float4 v0 = ((const float4*)src)[0], v1 = ((const float4*)src)[1];
      ushort tmp[8] __attribute__((aligned(16)));
      tmp[0] = bf16rne(v0.x); tmp[1] = bf16rne(v0.y);
      tmp[2] = bf16rne(v0.z); tmp[3] = bf16rne(v0.w);
      tmp[4] = bf16rne(v1.x); tmp[5] = bf16rne(v1.y);
      tmp[6] = bf16rne(v1.z); tmp[7] = bf16rne(v1.w);
      *(uint4*)(Ebf + ((size_t)dq * 1024 + blk * 16 + cl) * 8) = *(uint4*)tmp;
    }
    // e2 numpy-pairwise: 16 lanes/row, butterfly reproduces pairwise tree
    const int row = blk * 16 + (t >> 4);
    const int sub = t & 15, j = sub & 7, h = sub >> 3;
    const float* base = cb + row * 256 + h * 128 + j;
    float r = __fmul_rn(base[0], base[0]);
    for (int i = 1; i < 16; ++i) {
      float v = base[8 * i];
      r = __fadd_rn(r, __fmul_rn(v, v));
    }
#pragma unroll
    for (int m = 1; m < 16; m <<= 1) r = __fadd_rn(r, __shfl_xor(r, m, 64));
    if (sub == 0) e2[row] = r;
  }
}

// ---------- MFMA distance GEMM + argmin ----------
// Grid 1024 = 256 pos-tiles (128) x 4 k-splits (256 codes). Block 256 = 4
// waves (wm x wk), wave tile 64 pos x 128 codes = 4mi x 8kj of 16x16x32,
// acc[4][8] = 128 regs — fits (256,3)'s ~170 cap, NO spills. Chunks of 32 d:
// LDS 24 KB -> 3 blocks/CU, cross-block overlap hides DMA + barrier drains.
// Chunk-planar LDS: DMA lane-contiguous, frag reads = 16 contiguous 16B
// lanes (2-way, free). Score = e2 - 2*dot (x2 argmin-invariant); merge via
// atomicMin{fkey(score):32 | k:32}; first-min tie-break via low bits.
__global__ __launch_bounds__(256, 3) void k_argmin(
    const ushort* __restrict__ Xt, const ushort* __restrict__ Ebf,
    const float* __restrict__ e2g, unsigned long long* __restrict__ packed) {
  __shared__ alignas(16) ushort Xs[4 * 128 * 8];   // [dqL][pos][8]   8 KB
  __shared__ alignas(16) ushort Es[4 * 256 * 8];   // [dqL][code][8] 16 KB
  __shared__ float e2s[256];
  const int t = threadIdx.x;
  const int split = blockIdx.x & 3, tile = blockIdx.x >> 2;
  const int k0 = split * 256;
  const int lane = t & 63, w = t >> 6;
  const int wm = w >> 1, wk = w & 1;
  const int lrow = lane & 15, q = lane >> 4;

  e2s[t] = e2g[k0 + t];

  f4v acc[4][8];
#pragma unroll
  for (int mi = 0; mi < 4; ++mi)
#pragma unroll
    for (int kj = 0; kj < 8; ++kj) acc[mi][kj] = (f4v){0.f, 0.f, 0.f, 0.f};

  const ushort* Xg = Xt + (size_t)tile * 32768;    // 32 dq x 128 pos x 8

  for (int ch = 0; ch < 8; ++ch) {                 // 8 chunks of 32 d
    __syncthreads();                               // prev chunk consumed
#pragma unroll
    for (int ii = 0; ii < 2; ++ii) {               // X: 8 KB, 8 insts, 2/wave
      int j = w * 2 + ii;                          // dqL = j>>1, half = j&1
      gld_lds16(Xg + ((size_t)(ch * 4 + (j >> 1)) * 128 + (j & 1) * 64 + lane) * 8,
                &Xs[(((j >> 1) * 128) + (j & 1) * 64 + lane) * 8]);
    }
#pragma unroll
    for (int ii = 0; ii < 4; ++ii) {               // E: 16 KB, 16 insts, 4/wave
      int j = w * 4 + ii;                          // dqL = j>>2, quarter = j&3
      gld_lds16(Ebf + ((size_t)(ch * 4 + (j >> 2)) * 1024 + k0 + (j & 3) * 64 + lane) * 8,
                &Es[(((j >> 2) * 256) + (j & 3) * 64 + lane) * 8]);
    }
    __syncthreads();                               // drains DMA (vmcnt)
    s8v a_[4];                                     // q selects the 8-d group
#pragma unroll
    for (int mi = 0; mi < 4; ++mi)
      a_[mi] = *(const s8v*)&Xs[((size_t)q * 128 + wm * 64 + mi * 16 + lrow) * 8];
#pragma unroll
    for (int kj = 0; kj < 8; ++kj) {
      s8v b_ = *(const s8v*)&Es[((size_t)q * 256 + wk * 128 + kj * 16 + lrow) * 8];
#pragma unroll
      for (int mi = 0; mi < 4; ++mi)
        acc[mi][kj] = __builtin_amdgcn_mfma_f32_16x16x32_bf16(
            a_[mi], b_, acc[mi][kj], 0, 0, 0);
    }
  }

  float e2v[8];
#pragma unroll
  for (int kj = 0; kj < 8; ++kj) e2v[kj] = e2s[wk * 128 + kj * 16 + lrow];
#pragma unroll
  for (int mi = 0; mi < 4; ++mi) {
#pragma unroll
    for (int reg = 0; reg < 4; ++reg) {
      float best = 3.4e38f;
      int bk = 0;
#pragma unroll
      for (int kj = 0; kj < 8; ++kj) {             // kj ascending: first-min
        float s = __fadd_rn(e2v[kj], -2.f * acc[mi][kj][reg]);
        if (s < best) { best = s; bk = k0 + wk * 128 + kj * 16 + lrow; }
      }
#pragma unroll
      for (int m = 1; m < 16; m <<= 1) {           // reduce over lrow
        float ob = __shfl_xor(best, m, 64);
        int ok = __shfl_xor(bk, m, 64);
        if (ob < best || (ob == best && ok < bk)) { best = ob; bk = ok; }
      }
      if (lrow == 0) {
        int p = tile * 128 + wm * 64 + mi * 16 + q * 4 + reg;
        atomicMin(&packed[p],
                  ((unsigned long long)fkey(best) << 32) | (unsigned)bk);
      }
    }
  }
}

// ---------- gather + straight-through output + loss ----------
// Thread owns (pos-quad, 16 d): cb gathered as float4 over d (L2-resident),
// x/out as contiguous float4 over hw.
__global__ __launch_bounds__(256) void k_out(
    const float* __restrict__ latent, const float* __restrict__ cb,
    const unsigned long long* __restrict__ packed, float* __restrict__ out,
    float* __restrict__ loss) {
  __shared__ float red[4];
  const int gid = blockIdx.x * 256 + threadIdx.x;  // 131072
  const int pq = gid & 8191, dgg = gid >> 13;      // 16 d-groups of 16 d
  const int b = pq >> 8, hwq = pq & 255;
  const unsigned long long* pp = packed + (size_t)b * 1024 + hwq * 4;
  int idx[4];
#pragma unroll
  for (int e = 0; e < 4; ++e) idx[e] = (int)(unsigned)(pp[e] & 0xFFFFFFFFull);
  const float* Lb = latent + (size_t)b * (D_ * HW_) + hwq * 4;
  float* Ob = out + (size_t)b * (D_ * HW_) + hwq * 4;
  float part = 0.f;
#pragma unroll
  for (int j = 0; j < 4; ++j) {
    int d0 = dgg * 16 + j * 4;
    float ce[4][4] __attribute__((aligned(16)));   // [pos e][d r]
#pragma unroll
    for (int e = 0; e < 4; ++e)
      *(float4*)ce[e] = *(const float4*)(cb + (size_t)idx[e] * 256 + d0);
#pragma unroll
    for (int r = 0; r < 4; ++r) {
      float4 x = *(const float4*)(Lb + (size_t)(d0 + r) * HW_);
      float4 o;
      float df;
      df = __fsub_rn(ce[0][r], x.x); o.x = __fadd_rn(x.x, df); part = fmaf(df, df, part);
      df = __fsub_rn(ce[1][r], x.y); o.y = __fadd_rn(x.y, df); part = fmaf(df, df, part);
      df = __fsub_rn(ce[2][r], x.z); o.z = __fadd_rn(x.z, df); part = fmaf(df, df, part);
      df = __fsub_rn(ce[3][r], x.w); o.w = __fadd_rn(x.w, df); part = fmaf(df, df, part);
      *(float4*)(Ob + (size_t)(d0 + r) * HW_) = o;   // x + (q - x), NOT q
    }
  }
#pragma unroll
  for (int off = 32; off > 0; off >>= 1) part += __shfl_down(part, off, 64);
  if ((threadIdx.x & 63) == 0) red[threadIdx.x >> 6] = part;
  __syncthreads();
  if (threadIdx.x == 0)
    atomicAdd(loss, (red[0] + red[1] + red[2] + red[3]) * (1.25f / 8388608.0f));
}

extern "C" void kernel_launch(void* const* d_in, const int* in_sizes, int n_in,
                              void* d_out, int out_size, void* d_ws, size_t ws_size,
                              hipStream_t stream) {
  const float* latent = (const float*)d_in[0];
  const float* cb     = (const float*)d_in[1];
  float* out  = (float*)d_out;
  float* loss = out + (size_t)N_ * D_;             // element 8,388,608
  ushort* Xt  = (ushort*)out;                      // floats [0, 4194304)
  ushort* Ebf = (ushort*)(out + 4194304);          // floats [4194304, 4325376)
  float*  e2  = out + 4325376;                     // 1024 floats
  unsigned long long* packed = (unsigned long long*)d_ws;

  hipLaunchKernelGGL(k_prep,   dim3(320),  dim3(256), 0, stream,
                     latent, cb, Xt, Ebf, e2, packed, loss);
  hipLaunchKernelGGL(k_argmin, dim3(1024), dim3(256), 0, stream, Xt, Ebf, e2, packed);
  hipLaunchKernelGGL(k_out,    dim3(512),  dim3(256), 0, stream, latent, cb, packed, out, loss);
}

// Round 7
// 140.005 us; speedup vs baseline: 1.1191x; 1.1191x over previous
//
#include <hip/hip_runtime.h>
#include <stdint.h>

// VectorQuantizer on MI355X — round 6: double-buffered DMA staging with
// issue-after-barrier prefetch (one barrier per chunk), spill-free (256,2).
// latent [32,256,1024] fp32, codebook [1024,256] fp32.
// d_out float regions: Xt bf16 [0,4194304) | Ebf bf16 [4194304,4325376)
// | e2 [4325376,4326400) — consumed by k_argmin, overwritten by k_out's q_st.
// ws = packed u64[32768]: atomicMin of {monotone_score_key:32 | k:32}.

#define D_   256
#define HW_  1024
#define N_   32768
#define K_   1024

typedef __attribute__((ext_vector_type(8))) short  s8v;   // 8 bf16 (4 VGPR)
typedef __attribute__((ext_vector_type(4))) float  f4v;   // MFMA acc

__device__ __forceinline__ ushort bf16rne(float x) {
  unsigned u = __float_as_uint(x);
  return (ushort)((u + 0x7FFFu + ((u >> 16) & 1u)) >> 16);
}

// monotone map: unsigned order of key == float order (handles negatives)
__device__ __forceinline__ unsigned fkey(float f) {
  unsigned u = __float_as_uint(f);
  return u ^ (unsigned)(((int)u >> 31) | 0x80000000);
}

// async global->LDS DMA, 16 B/lane; LDS dest = wave-uniform base + lane*16
__device__ __forceinline__ void gld_lds16(const void* g, void* l) {
  __builtin_amdgcn_global_load_lds(
      (const __attribute__((address_space(1))) unsigned int*)g,
      (__attribute__((address_space(3))) unsigned int*)l, 16, 0, 0);
}

// ---------- merged prep: blocks 0..255 xprep, 256..319 eprep ----------
__global__ __launch_bounds__(256) void k_prep(const float* __restrict__ latent,
                                              const float* __restrict__ cb,
                                              ushort* __restrict__ Xt,
                                              ushort* __restrict__ Ebf,
                                              float* __restrict__ e2,
                                              unsigned long long* __restrict__ packed,
                                              float* __restrict__ loss) {
  const int t = threadIdx.x;
  if (blockIdx.x < 256) {
    __shared__ float Xf[64 * 132];                 // 33 KB, pitch 132 (16B-aligned)
    const int tile = blockIdx.x;                   // 256 tiles x 128 pos
    int gid = tile * 256 + t;
    if (gid < N_) packed[gid] = ~0ull;             // init argmin keys
    const int b = tile >> 3, hw0 = (tile & 7) * 128;
    const float* Lb = latent + (size_t)b * (D_ * HW_) + hw0;
    for (int s = 0; s < 4; ++s) {                  // 4 slabs of 64 d
      __syncthreads();
#pragma unroll
      for (int it = 0; it < 8; ++it) {             // load [64 d][128 hw] fp32
        int idx = it * 256 + t;
        int d = idx >> 5, hq = idx & 31;
        float4 v = *(const float4*)(Lb + (size_t)(s * 64 + d) * HW_ + hq * 4);
        *(float4*)&Xf[d * 132 + hq * 4] = v;
      }
      __syncthreads();
#pragma unroll
      for (int it = 0; it < 4; ++it) {             // transpose-convert out
        int idx = it * 256 + t;
        int pos = idx & 127, dq = idx >> 7;        // dq 0..7 within slab
        ushort tmp[8] __attribute__((aligned(16)));
#pragma unroll
        for (int e = 0; e < 8; ++e) tmp[e] = bf16rne(Xf[(dq * 8 + e) * 132 + pos]);
        *(uint4*)(Xt + ((size_t)(tile * 32 + s * 8 + dq) * 128 + pos) * 8) =
            *(uint4*)tmp;
      }
    }
  } else {
    const int blk = blockIdx.x - 256;              // 64 blocks x 16 codes
    if (blk == 0 && t == 0) *loss = 0.f;
#pragma unroll
    for (int it = 0; it < 2; ++it) {
      int c = it * 256 + t;                        // 512 chunks/block
      int cl = c & 15, dq = c >> 4;                // code-local, d-chunk
      const float* src = cb + (size_t)(blk * 16 + cl) * 256 + dq * 8;
      float4 v0 = ((const float4*)src)[0], v1 = ((const float4*)src)[1];
      ushort tmp[8] __attribute__((aligned(16)));
      tmp[0] = bf16rne(v0.x); tmp[1] = bf16rne(v0.y);
      tmp[2] = bf16rne(v0.z); tmp[3] = bf16rne(v0.w);
      tmp[4] = bf16rne(v1.x); tmp[5] = bf16rne(v1.y);
      tmp[6] = bf16rne(v1.z); tmp[7] = bf16rne(v1.w);
      *(uint4*)(Ebf + ((size_t)dq * 1024 + blk * 16 + cl) * 8) = *(uint4*)tmp;
    }
    // e2 numpy-pairwise: 16 lanes/row, butterfly reproduces pairwise tree
    const int row = blk * 16 + (t >> 4);
    const int sub = t & 15, j = sub & 7, h = sub >> 3;
    const float* base = cb + row * 256 + h * 128 + j;
    float r = __fmul_rn(base[0], base[0]);
    for (int i = 1; i < 16; ++i) {
      float v = base[8 * i];
      r = __fadd_rn(r, __fmul_rn(v, v));
    }
#pragma unroll
    for (int m = 1; m < 16; m <<= 1) r = __fadd_rn(r, __shfl_xor(r, m, 64));
    if (sub == 0) e2[row] = r;
  }
}

// ---------- MFMA distance GEMM + argmin (double-buffered) ----------
// Grid 1024 = 256 pos-tiles (128) x 4 k-splits (256 codes). Block 256 = 4
// waves (wm x wk), wave tile 64 pos x 128 codes = 4mi x 8kj of 16x16x32.
// acc[4][8] = 128 acc regs + ~128 arch regs -> needs the (256,2) 256-reg
// budget (rounds 3&5 lesson: anything tighter spills to scratch).
// Per 32-d chunk: ONE barrier; DMA for chunk ch+1 issues right after the
// barrier and lands during compute(ch) -> next barrier's vmcnt(0) drain is
// near-free (vs R4/R5's issue-then-barrier which exposed full latency).
// Chunk-planar layout keeps DMA lane-contiguous and frag reads 2-way/free.
__global__ __launch_bounds__(256, 2) void k_argmin(
    const ushort* __restrict__ Xt, const ushort* __restrict__ Ebf,
    const float* __restrict__ e2g, unsigned long long* __restrict__ packed) {
  __shared__ alignas(16) ushort Xs[2][4 * 128 * 8];   // 2 x 8 KB
  __shared__ alignas(16) ushort Es[2][4 * 256 * 8];   // 2 x 16 KB
  __shared__ float e2s[256];
  const int t = threadIdx.x;
  const int split = blockIdx.x & 3, tile = blockIdx.x >> 2;
  const int k0 = split * 256;
  const int lane = t & 63, w = t >> 6;
  const int wm = w >> 1, wk = w & 1;
  const int lrow = lane & 15, q = lane >> 4;

  e2s[t] = e2g[k0 + t];

  f4v acc[4][8];
#pragma unroll
  for (int mi = 0; mi < 4; ++mi)
#pragma unroll
    for (int kj = 0; kj < 8; ++kj) acc[mi][kj] = (f4v){0.f, 0.f, 0.f, 0.f};

  const ushort* Xg = Xt + (size_t)tile * 32768;    // 32 dq x 128 pos x 8
  const ushort* Eg = Ebf;

  // stage chunk ch (32 d) into buffer bb
#define STAGE(ch, bb)                                                          \
  {                                                                            \
    _Pragma("unroll")                                                          \
    for (int ii = 0; ii < 2; ++ii) {             /* X: 8 KB, 8 insts */        \
      int j = w * 2 + ii;                                                      \
      gld_lds16(Xg + ((size_t)((ch) * 4 + (j >> 1)) * 128 + (j & 1) * 64 + lane) * 8, \
                &Xs[bb][(((j >> 1) * 128) + (j & 1) * 64 + lane) * 8]);        \
    }                                                                          \
    _Pragma("unroll")                                                          \
    for (int ii = 0; ii < 4; ++ii) {             /* E: 16 KB, 16 insts */      \
      int j = w * 4 + ii;                                                      \
      gld_lds16(Eg + ((size_t)((ch) * 4 + (j >> 2)) * 1024 + k0 + (j & 3) * 64 + lane) * 8, \
                &Es[bb][(((j >> 2) * 256) + (j & 3) * 64 + lane) * 8]);        \
    }                                                                          \
  }

  STAGE(0, 0);
  for (int ch = 0; ch < 8; ++ch) {                 // 8 chunks of 32 d
    const int bb = ch & 1;
    __syncthreads();                               // drains DMA(ch) [covered by prev compute]
    if (ch < 7) STAGE(ch + 1, bb ^ 1);             // prefetch lands during compute below
    s8v a_[4];                                     // q selects the 8-d group
#pragma unroll
    for (int mi = 0; mi < 4; ++mi)
      a_[mi] = *(const s8v*)&Xs[bb][((size_t)q * 128 + wm * 64 + mi * 16 + lrow) * 8];
#pragma unroll
    for (int kj = 0; kj < 8; ++kj) {
      s8v b_ = *(const s8v*)&Es[bb][((size_t)q * 256 + wk * 128 + kj * 16 + lrow) * 8];
#pragma unroll
      for (int mi = 0; mi < 4; ++mi)
        acc[mi][kj] = __builtin_amdgcn_mfma_f32_16x16x32_bf16(
            a_[mi], b_, acc[mi][kj], 0, 0, 0);
    }
    if (ch < 7) __syncthreads();                   // reads of buf bb done before next overwrite
  }
#undef STAGE

  float e2v[8];
#pragma unroll
  for (int kj = 0; kj < 8; ++kj) e2v[kj] = e2s[wk * 128 + kj * 16 + lrow];
#pragma unroll
  for (int mi = 0; mi < 4; ++mi) {
#pragma unroll
    for (int reg = 0; reg < 4; ++reg) {
      float best = 3.4e38f;
      int bk = 0;
#pragma unroll
      for (int kj = 0; kj < 8; ++kj) {             // kj ascending: first-min
        float s = __fadd_rn(e2v[kj], -2.f * acc[mi][kj][reg]);
        if (s < best) { best = s; bk = k0 + wk * 128 + kj * 16 + lrow; }
      }
#pragma unroll
      for (int m = 1; m < 16; m <<= 1) {           // reduce over lrow
        float ob = __shfl_xor(best, m, 64);
        int ok = __shfl_xor(bk, m, 64);
        if (ob < best || (ob == best && ok < bk)) { best = ob; bk = ok; }
      }
      if (lrow == 0) {
        int p = tile * 128 + wm * 64 + mi * 16 + q * 4 + reg;
        atomicMin(&packed[p],
                  ((unsigned long long)fkey(best) << 32) | (unsigned)bk);
      }
    }
  }
}

// ---------- gather + straight-through output + loss ----------
// HBM-roofline kernel (~256 MB mandatory): latent read + q_st write as
// contiguous float4 over hw; cb gathered as float4 over d (L2-resident).
__global__ __launch_bounds__(256) void k_out(
    const float* __restrict__ latent, const float* __restrict__ cb,
    const unsigned long long* __restrict__ packed, float* __restrict__ out,
    float* __restrict__ loss) {
  __shared__ float red[4];
  const int gid = blockIdx.x * 256 + threadIdx.x;  // 131072
  const int pq = gid & 8191, dgg = gid >> 13;      // 16 d-groups of 16 d
  const int b = pq >> 8, hwq = pq & 255;
  const unsigned long long* pp = packed + (size_t)b * 1024 + hwq * 4;
  int idx[4];
#pragma unroll
  for (int e = 0; e < 4; ++e) idx[e] = (int)(unsigned)(pp[e] & 0xFFFFFFFFull);
  const float* Lb = latent + (size_t)b * (D_ * HW_) + hwq * 4;
  float* Ob = out + (size_t)b * (D_ * HW_) + hwq * 4;
  float part = 0.f;
#pragma unroll
  for (int j = 0; j < 4; ++j) {
    int d0 = dgg * 16 + j * 4;
    float ce[4][4] __attribute__((aligned(16)));   // [pos e][d r]
#pragma unroll
    for (int e = 0; e < 4; ++e)
      *(float4*)ce[e] = *(const float4*)(cb + (size_t)idx[e] * 256 + d0);
#pragma unroll
    for (int r = 0; r < 4; ++r) {
      float4 x = *(const float4*)(Lb + (size_t)(d0 + r) * HW_);
      float4 o;
      float df;
      df = __fsub_rn(ce[0][r], x.x); o.x = __fadd_rn(x.x, df); part = fmaf(df, df, part);
      df = __fsub_rn(ce[1][r], x.y); o.y = __fadd_rn(x.y, df); part = fmaf(df, df, part);
      df = __fsub_rn(ce[2][r], x.z); o.z = __fadd_rn(x.z, df); part = fmaf(df, df, part);
      df = __fsub_rn(ce[3][r], x.w); o.w = __fadd_rn(x.w, df); part = fmaf(df, df, part);
      *(float4*)(Ob + (size_t)(d0 + r) * HW_) = o;   // x + (q - x), NOT q
    }
  }
#pragma unroll
  for (int off = 32; off > 0; off >>= 1) part += __shfl_down(part, off, 64);
  if ((threadIdx.x & 63) == 0) red[threadIdx.x >> 6] = part;
  __syncthreads();
  if (threadIdx.x == 0)
    atomicAdd(loss, (red[0] + red[1] + red[2] + red[3]) * (1.25f / 8388608.0f));
}

extern "C" void kernel_launch(void* const* d_in, const int* in_sizes, int n_in,
                              void* d_out, int out_size, void* d_ws, size_t ws_size,
                              hipStream_t stream) {
  const float* latent = (const float*)d_in[0];
  const float* cb     = (const float*)d_in[1];
  float* out  = (float*)d_out;
  float* loss = out + (size_t)N_ * D_;             // element 8,388,608
  ushort* Xt  = (ushort*)out;                      // floats [0, 4194304)
  ushort* Ebf = (ushort*)(out + 4194304);          // floats [4194304, 4325376)
  float*  e2  = out + 4325376;                     // 1024 floats
  unsigned long long* packed = (unsigned long long*)d_ws;

  hipLaunchKernelGGL(k_prep,   dim3(320),  dim3(256), 0, stream,
                     latent, cb, Xt, Ebf, e2, packed, loss);
  hipLaunchKernelGGL(k_argmin, dim3(1024), dim3(256), 0, stream, Xt, Ebf, e2, packed);
  hipLaunchKernelGGL(k_out,    dim3(512),  dim3(256), 0, stream, latent, cb, packed, out, loss);
}

// Round 8
// 128.455 us; speedup vs baseline: 1.2197x; 1.0899x over previous
//
#include <hip/hip_runtime.h>
#include <stdint.h>

// VectorQuantizer on MI355X — round 7: single fused tile kernel.
// Per 64-pos tile: stage latent->bf16 LDS once (persistent A-operand),
// MFMA over all 1024 codes (Es DMA-staged from L2-resident Ebf), in-block
// argmin merge, then gather+ST-output+loss — no Xt, no packed, no k_out.
// latent [32,256,1024] fp32, codebook [1024,256] fp32.
// ws = [ Ebf bf16 chunk-planar [dq32][code1024][8] (512 KB) | e2 f32[1024] ].

#define D_   256
#define HW_  1024
#define N_   32768
#define K_   1024

typedef __attribute__((ext_vector_type(8))) short  s8v;   // 8 bf16 (4 VGPR)
typedef __attribute__((ext_vector_type(4))) float  f4v;   // MFMA acc

__device__ __forceinline__ ushort bf16rne(float x) {
  unsigned u = __float_as_uint(x);
  return (ushort)((u + 0x7FFFu + ((u >> 16) & 1u)) >> 16);
}

// monotone map: unsigned order of key == float order (handles negatives)
__device__ __forceinline__ unsigned fkey(float f) {
  unsigned u = __float_as_uint(f);
  return u ^ (unsigned)(((int)u >> 31) | 0x80000000);
}

// async global->LDS DMA, 16 B/lane; LDS dest = wave-uniform base + lane*16
__device__ __forceinline__ void gld_lds16(const void* g, void* l) {
  __builtin_amdgcn_global_load_lds(
      (const __attribute__((address_space(1))) unsigned int*)g,
      (__attribute__((address_space(3))) unsigned int*)l, 16, 0, 0);
}

// ---------- codebook -> bf16 chunk-planar Ebf + numpy-pairwise e2 + loss=0 ----------
__global__ __launch_bounds__(256) void k_eprep(const float* __restrict__ cb,
                                               ushort* __restrict__ Ebf,
                                               float* __restrict__ e2,
                                               float* __restrict__ loss) {
  const int t = threadIdx.x, blk = blockIdx.x;   // 64 blocks x 16 codes
  if (blk == 0 && t == 0) *loss = 0.f;
#pragma unroll
  for (int it = 0; it < 2; ++it) {
    int c = it * 256 + t;                        // 512 chunks/block
    int cl = c & 15, dq = c >> 4;                // code-local, d-chunk
    const float* src = cb + (size_t)(blk * 16 + cl) * 256 + dq * 8;
    float4 v0 = ((const float4*)src)[0], v1 = ((const float4*)src)[1];
    ushort tmp[8] __attribute__((aligned(16)));
    tmp[0] = bf16rne(v0.x); tmp[1] = bf16rne(v0.y);
    tmp[2] = bf16rne(v0.z); tmp[3] = bf16rne(v0.w);
    tmp[4] = bf16rne(v1.x); tmp[5] = bf16rne(v1.y);
    tmp[6] = bf16rne(v1.z); tmp[7] = bf16rne(v1.w);
    *(uint4*)(Ebf + ((size_t)dq * 1024 + blk * 16 + cl) * 8) = *(uint4*)tmp;
  }
  // e2 numpy-pairwise: 16 lanes/row, butterfly reproduces pairwise tree
  const int row = blk * 16 + (t >> 4);
  const int sub = t & 15, j = sub & 7, h = sub >> 3;
  const float* base = cb + row * 256 + h * 128 + j;
  float r = __fmul_rn(base[0], base[0]);
  for (int i = 1; i < 16; ++i) {
    float v = base[8 * i];
    r = __fadd_rn(r, __fmul_rn(v, v));
  }
#pragma unroll
  for (int m = 1; m < 16; m <<= 1) r = __fadd_rn(r, __shfl_xor(r, m, 64));
  if (sub == 0) e2[row] = r;
}

// ---------- fused: convert + MFMA-argmin over K=1024 + gather + out + loss ----------
// Grid 512 tiles (64 pos, hw-contiguous). Block 256 = 4 waves.
// LDS: Xbf 32 KB persistent A-operand [dq(32)][pos(64)][8]; Es 32 KB
// [dqL(4)][code(512)][8] (phase-A float scratch overlays it); e2s 4 KB.
// Wave tile 64 pos x 128 codes = acc[4][8] (128 acc regs; (256,2) budget —
// rounds 3/5 lesson: tighter caps spill). Frag-read patterns identical to
// R4/R6's measured-zero-conflict layout. Scores bit-identical to R4/R6:
// fadd(e2, -2*dot), first-min by (score, k) via atomicMin on {fkey|k}.
__global__ __launch_bounds__(256, 2) void k_fused(
    const float* __restrict__ latent, const float* __restrict__ cb,
    const ushort* __restrict__ Ebf, const float* __restrict__ e2g,
    float* __restrict__ out, float* __restrict__ loss) {
  __shared__ alignas(16) ushort Xbf[32 * 64 * 8];   // 32 KB
  __shared__ alignas(16) ushort Es[4 * 512 * 8];    // 32 KB (+phase-A overlay)
  __shared__ float e2s[1024];
  __shared__ unsigned long long bests[64];
  __shared__ float red[4];

  const int t = threadIdx.x, tile = blockIdx.x;     // 512 tiles x 64 pos
  const int b = tile >> 4, hw0 = (tile & 15) * 64;
  const int lane = t & 63, w = t >> 6;
  const int lrow = lane & 15, q = lane >> 4;

  ((float4*)e2s)[t] = ((const float4*)e2g)[t];      // 1024 floats
  if (t < 64) bests[t] = ~0ull;

  // ---- Phase A: latent tile -> Xbf (bf16, chunk-planar), via Es overlay ----
  float* Xf = (float*)Es;                           // 64 x 68 fp32 = 17.4 KB
  const float* Lb = latent + (size_t)b * (D_ * HW_) + hw0;
  for (int s = 0; s < 4; ++s) {                     // slabs of 64 d
    __syncthreads();
#pragma unroll
    for (int it = 0; it < 4; ++it) {                // [64 d][64 hw] float4
      int id = it * 256 + t;
      int d = id >> 4, hq = id & 15;
      *(float4*)&Xf[d * 68 + hq * 4] =
          *(const float4*)(Lb + (size_t)(s * 64 + d) * HW_ + hq * 4);
    }
    __syncthreads();
#pragma unroll
    for (int it = 0; it < 2; ++it) {                // transpose-convert
      int id = it * 256 + t;
      int pos = id & 63, dqs = id >> 6;             // dqs 0..7 in slab
      ushort tmp[8] __attribute__((aligned(16)));
#pragma unroll
      for (int e = 0; e < 8; ++e) tmp[e] = bf16rne(Xf[(dqs * 8 + e) * 68 + pos]);
      *(uint4*)&Xbf[((size_t)(s * 8 + dqs) * 64 + pos) * 8] = *(uint4*)tmp;
    }
  }

  // ---- Phase B: K-loop over 1024 codes, argmin ----
  float best[4][4];
  int bestk[4][4];
#pragma unroll
  for (int mi = 0; mi < 4; ++mi)
#pragma unroll
    for (int reg = 0; reg < 4; ++reg) { best[mi][reg] = 3.4e38f; bestk[mi][reg] = 0; }

  for (int ms = 0; ms < 2; ++ms) {                  // 2 halves of 512 codes
    const int kh = ms * 512;
    f4v acc[4][8];
#pragma unroll
    for (int mi = 0; mi < 4; ++mi)
#pragma unroll
      for (int kj = 0; kj < 8; ++kj) acc[mi][kj] = (f4v){0.f, 0.f, 0.f, 0.f};

    for (int ch = 0; ch < 8; ++ch) {                // chunks of 32 d
      __syncthreads();                              // Es consumable (or overlay done)
#pragma unroll
      for (int ii = 0; ii < 8; ++ii) {              // stage Es: 32 KB, 8 insts/wave
        int j = w * 8 + ii;                         // dqL = j>>3, grp = j&7
        gld_lds16(Ebf + ((size_t)(ch * 4 + (j >> 3)) * 1024 + kh + (j & 7) * 64 + lane) * 8,
                  &Es[(((j >> 3) * 512) + (j & 7) * 64 + lane) * 8]);
      }
      __syncthreads();                              // drain DMA
      s8v a_[4];                                    // q picks dq within chunk
#pragma unroll
      for (int mi = 0; mi < 4; ++mi)
        a_[mi] = *(const s8v*)&Xbf[((size_t)(ch * 4 + q) * 64 + mi * 16 + lrow) * 8];
#pragma unroll
      for (int kj = 0; kj < 8; ++kj) {
        s8v b_ = *(const s8v*)&Es[((size_t)q * 512 + w * 128 + kj * 16 + lrow) * 8];
#pragma unroll
        for (int mi = 0; mi < 4; ++mi)
          acc[mi][kj] = __builtin_amdgcn_mfma_f32_16x16x32_bf16(
              a_[mi], b_, acc[mi][kj], 0, 0, 0);
      }
    }
    // per-half epilogue into running per-lane best (codes kh + w*128 + ...)
#pragma unroll
    for (int kj = 0; kj < 8; ++kj) {                // kj ascending: first-min
      int code = kh + w * 128 + kj * 16 + lrow;
      float e2v = e2s[code];
#pragma unroll
      for (int mi = 0; mi < 4; ++mi)
#pragma unroll
        for (int reg = 0; reg < 4; ++reg) {
          float s = __fadd_rn(e2v, -2.f * acc[mi][kj][reg]);
          if (s < best[mi][reg]) { best[mi][reg] = s; bestk[mi][reg] = code; }
        }
    }
  }
  // reduce over the 16 lrow lanes, then cross-wave via LDS atomicMin
#pragma unroll
  for (int mi = 0; mi < 4; ++mi)
#pragma unroll
    for (int reg = 0; reg < 4; ++reg) {
      float bv = best[mi][reg];
      int bk = bestk[mi][reg];
#pragma unroll
      for (int m = 1; m < 16; m <<= 1) {
        float ob = __shfl_xor(bv, m, 64);
        int ok = __shfl_xor(bk, m, 64);
        if (ob < bv || (ob == bv && ok < bk)) { bv = ob; bk = ok; }
      }
      if (lrow == 0) {
        int pos = mi * 16 + q * 4 + reg;
        atomicMin(&bests[pos],
                  ((unsigned long long)fkey(bv) << 32) | (unsigned)bk);
      }
    }
  __syncthreads();                                  // bests final

  // ---- Phase C: gather + straight-through output + loss ----
  const int posq = t & 15;                          // constant per thread
  int kk[4];
#pragma unroll
  for (int e = 0; e < 4; ++e)
    kk[e] = (int)(unsigned)(bests[posq * 4 + e] & 0xFFFFFFFFull);
  float* Ob = out + (size_t)b * (D_ * HW_) + hw0 + posq * 4;
  const float* Lb2 = Lb + posq * 4;
  float part = 0.f;
#pragma unroll 4
  for (int it = 0; it < 16; ++it) {
    int d = it * 16 + (t >> 4);
    float4 x = *(const float4*)(Lb2 + (size_t)d * HW_);
    float4 o;
    float qv, df;
    qv = cb[(size_t)kk[0] * 256 + d]; df = __fsub_rn(qv, x.x); o.x = __fadd_rn(x.x, df); part = fmaf(df, df, part);
    qv = cb[(size_t)kk[1] * 256 + d]; df = __fsub_rn(qv, x.y); o.y = __fadd_rn(x.y, df); part = fmaf(df, df, part);
    qv = cb[(size_t)kk[2] * 256 + d]; df = __fsub_rn(qv, x.z); o.z = __fadd_rn(x.z, df); part = fmaf(df, df, part);
    qv = cb[(size_t)kk[3] * 256 + d]; df = __fsub_rn(qv, x.w); o.w = __fadd_rn(x.w, df); part = fmaf(df, df, part);
    *(float4*)(Ob + (size_t)d * HW_) = o;           // x + (q - x), NOT q
  }
#pragma unroll
  for (int off = 32; off > 0; off >>= 1) part += __shfl_down(part, off, 64);
  if (lane == 0) red[w] = part;
  __syncthreads();
  if (t == 0)
    atomicAdd(loss, (red[0] + red[1] + red[2] + red[3]) * (1.25f / 8388608.0f));
}

extern "C" void kernel_launch(void* const* d_in, const int* in_sizes, int n_in,
                              void* d_out, int out_size, void* d_ws, size_t ws_size,
                              hipStream_t stream) {
  const float* latent = (const float*)d_in[0];
  const float* cb     = (const float*)d_in[1];
  float* out  = (float*)d_out;
  float* loss = out + (size_t)N_ * D_;             // element 8,388,608
  ushort* Ebf = (ushort*)d_ws;                     // 512 KB chunk-planar bf16
  float*  e2  = (float*)((char*)d_ws + (size_t)K_ * D_ * sizeof(ushort));

  hipLaunchKernelGGL(k_eprep, dim3(64),  dim3(256), 0, stream, cb, Ebf, e2, loss);
  hipLaunchKernelGGL(k_fused, dim3(512), dim3(256), 0, stream,
                     latent, cb, Ebf, e2, out, loss);
}